// Round 5
// baseline (518.447 us; speedup 1.0000x reference)
//
#include <hip/hip_runtime.h>

// B=32, S=2048, F=768, H=8  — all fp32
// ws layout (floats): att/w [B*H*S]=524288 | gate [524288] | pooled [B*F*H]=196608

// 512 threads = 8 waves per block; each wave computes 2 rows x 16 logits.
// Reduce via reduce-scatter (32 shuffles/wave instead of 384 butterfly ops).
__global__ __launch_bounds__(512) void kLogits(const float* __restrict__ x,
    const float* __restrict__ Wa, const float* __restrict__ ba,
    const float* __restrict__ Wg, const float* __restrict__ bg,
    float* __restrict__ att, float* __restrict__ gate)
{
    __shared__ float Wl[16 * 768];   // rows 0..7 = W_att, 8..15 = W_gate
    int t = threadIdx.x;
    for (int i = t; i < 12288; i += 512)
        Wl[i] = (i < 6144) ? Wa[i] : Wg[i - 6144];
    __syncthreads();

    int wid = t >> 6, lane = t & 63;
    long row0 = (long)blockIdx.x * 16 + wid * 2;   // each wave: 2 rows

    float4 xv[2][3];
    #pragma unroll
    for (int r = 0; r < 2; r++) {
        const float4* xp = reinterpret_cast<const float4*>(x + (row0 + r) * 768 + lane * 4);
        #pragma unroll
        for (int k = 0; k < 3; k++) xv[r][k] = xp[k * 64];
    }

    // acc[h*2 + r]
    float acc[32];
    #pragma unroll
    for (int i = 0; i < 32; i++) acc[i] = 0.f;

    #pragma unroll
    for (int h = 0; h < 16; h++) {
        const float4* wp = reinterpret_cast<const float4*>(&Wl[h * 768 + lane * 4]);
        #pragma unroll
        for (int k = 0; k < 3; k++) {
            float4 wv = wp[k * 64];
            #pragma unroll
            for (int r = 0; r < 2; r++) {
                acc[h * 2 + r] += wv.x * xv[r][k].x;
                acc[h * 2 + r] += wv.y * xv[r][k].y;
                acc[h * 2 + r] += wv.z * xv[r][k].z;
                acc[h * 2 + r] += wv.w * xv[r][k].w;
            }
        }
    }

    // reduce-scatter: after 5 halving steps + 1 final add, lane L (and L^32)
    // holds the full 64-lane sum of acc[bitrev5(L&31)].
#define RSTEP(STEP, HALF) { \
    int bit = (lane >> STEP) & 1; \
    _Pragma("unroll") \
    for (int i = 0; i < HALF; i++) { \
        float send = bit ? acc[i] : acc[i + HALF]; \
        float recv = __shfl_xor(send, 1 << STEP, 64); \
        acc[i] = (bit ? acc[i + HALF] : acc[i]) + recv; \
    } }
    RSTEP(0, 16) RSTEP(1, 8) RSTEP(2, 4) RSTEP(3, 2) RSTEP(4, 1)
#undef RSTEP
    acc[0] += __shfl_xor(acc[0], 32, 64);

    if (lane < 32) {
        int idx = ((lane & 1) << 4) | (((lane >> 1) & 1) << 3) | (((lane >> 2) & 1) << 2)
                | (((lane >> 3) & 1) << 1) | ((lane >> 4) & 1);
        int h = idx >> 1, r = idx & 1;
        long row = row0 + r;
        int b = (int)(row >> 11);
        int s = (int)(row & 2047);
        if (h < 8) {
            att[((b << 3) + h) * 2048 + s] = acc[0] + ba[h];
        } else {
            float g = acc[0] + bg[h - 8];
            gate[((b << 3) + h - 8) * 2048 + s] = 1.f / (1.f + __expf(-g));
        }
    }
}

// block per (b,h): softmax over S, fold in sigmoid(gate), write w in place of att
__global__ __launch_bounds__(256) void kSoftmax(float* __restrict__ att,
                                                const float* __restrict__ gate)
{
    int bh = blockIdx.x;
    int t = threadIdx.x;
    long base = (long)bh * 2048;

    float v[8];
    #pragma unroll
    for (int i = 0; i < 8; i++) v[i] = att[base + t + (i << 8)];

    float m = v[0];
    #pragma unroll
    for (int i = 1; i < 8; i++) m = fmaxf(m, v[i]);
    #pragma unroll
    for (int off = 1; off < 64; off <<= 1) m = fmaxf(m, __shfl_xor(m, off, 64));

    __shared__ float sm[4], ssum[4];
    int wid = t >> 6, lane = t & 63;
    if (lane == 0) sm[wid] = m;
    __syncthreads();
    float M = fmaxf(fmaxf(sm[0], sm[1]), fmaxf(sm[2], sm[3]));

    float e[8]; float s = 0.f;
    #pragma unroll
    for (int i = 0; i < 8; i++) { e[i] = __expf(v[i] - M); s += e[i]; }
    #pragma unroll
    for (int off = 1; off < 64; off <<= 1) s += __shfl_xor(s, off, 64);
    if (lane == 0) ssum[wid] = s;
    __syncthreads();
    float inv = 1.f / (ssum[0] + ssum[1] + ssum[2] + ssum[3]);

    #pragma unroll
    for (int i = 0; i < 8; i++) {
        long idx = base + t + (i << 8);
        att[idx] = e[i] * inv * gate[idx];
    }
}

// 1024 threads, block per (s-chunk=256, b): pooled[b,f,h] += sum_s w[b,h,s]*x[b,s,f]
// 256 blocks = exactly 1/CU, 16 waves/CU.
__global__ __launch_bounds__(1024) void kPool(const float* __restrict__ x,
                                              const float* __restrict__ w,
                                              float* __restrict__ pooled)
{
    int sc = blockIdx.x, b = blockIdx.y;
    int s0 = sc << 8;
    __shared__ float wl[2048];            // [8 h][256 s]
    int t = threadIdx.x;
    for (int i = t; i < 2048; i += 1024)
        wl[i] = w[((long)((b << 3) + (i >> 8)) << 11) + s0 + (i & 255)];
    __syncthreads();

    int tf = t & 255, sg = t >> 8;        // sg in 0..3, 64 s each

    float acc[8][3];
    #pragma unroll
    for (int h = 0; h < 8; h++)
        #pragma unroll
        for (int j = 0; j < 3; j++) acc[h][j] = 0.f;

    const float* xb = x + ((long)(b << 11) + s0 + sg * 64) * 768 + tf;
    int sbase = sg << 6;
    for (int i = 0; i < 64; i++) {
        float x0 = xb[0], x1 = xb[256], x2 = xb[512];
        #pragma unroll
        for (int h = 0; h < 8; h++) {
            float wv = wl[(h << 8) + sbase + i];   // broadcast across wave
            acc[h][0] += wv * x0;
            acc[h][1] += wv * x1;
            acc[h][2] += wv * x2;
        }
        xb += 768;
    }

    #pragma unroll
    for (int j = 0; j < 3; j++) {
        float* pp = pooled + b * 6144 + (tf + (j << 8)) * 8;
        #pragma unroll
        for (int h = 0; h < 8; h++) atomicAdd(pp + h, acc[h][j]);
    }
}

__global__ __launch_bounds__(256) void kOutInit(const float* __restrict__ bo,
                                                float* __restrict__ out)
{
    int idx = blockIdx.x * 256 + threadIdx.x;   // 24576 total
    out[idx] = bo[idx % 768];
}

// out[b,fo] += sum_k pooled[b,k]*Wout[fo,k]; block = (k-chunk 256, fo-chunk 16)
__global__ __launch_bounds__(256) void kGemm(const float* __restrict__ pooled,
                                             const float* __restrict__ Wout,
                                             float* __restrict__ out)
{
    int kg = blockIdx.x, fg = blockIdx.y;
    int k0 = kg << 8, fo0 = fg << 4;
    __shared__ float pl[32 * 258];   // +2 pad: float2-aligned, 2-way conflicts free
    __shared__ float wl[16 * 258];
    int t = threadIdx.x;
    #pragma unroll 4
    for (int i = 0; i < 32; i++) pl[i * 258 + t] = pooled[i * 6144 + k0 + t];
    #pragma unroll 4
    for (int j = 0; j < 16; j++) wl[j * 258 + t] = Wout[(fo0 + j) * 6144 + k0 + t];
    __syncthreads();

    int b = t & 31, fq = t >> 5;
    const float2* pp = reinterpret_cast<const float2*>(pl + b * 258);
    const float2* u  = reinterpret_cast<const float2*>(wl + fq * 258);
    const float2* vv = reinterpret_cast<const float2*>(wl + (fq + 8) * 258);
    float a0 = 0.f, a1 = 0.f;
    #pragma unroll 8
    for (int kk = 0; kk < 128; kk++) {
        float2 p = pp[kk], w0 = u[kk], w1 = vv[kk];
        a0 += p.x * w0.x + p.y * w0.y;
        a1 += p.x * w1.x + p.y * w1.y;
    }
    atomicAdd(&out[b * 768 + fo0 + fq], a0);
    atomicAdd(&out[b * 768 + fo0 + 8 + fq], a1);
}

extern "C" void kernel_launch(void* const* d_in, const int* in_sizes, int n_in,
                              void* d_out, int out_size, void* d_ws, size_t ws_size,
                              hipStream_t stream)
{
    const float* x  = (const float*)d_in[0];
    const float* Wa = (const float*)d_in[1];
    const float* ba = (const float*)d_in[2];
    const float* Wg = (const float*)d_in[3];
    const float* bg = (const float*)d_in[4];
    const float* Wo = (const float*)d_in[5];
    const float* bo = (const float*)d_in[6];
    float* out = (float*)d_out;

    float* att    = (float*)d_ws;          // 524288 floats (becomes w in place)
    float* gate   = att + 524288;          // 524288 floats
    float* pooled = gate + 524288;         // 196608 floats

    hipMemsetAsync(pooled, 0, 196608 * sizeof(float), stream);

    kLogits <<<4096,          512, 0, stream>>>(x, Wa, ba, Wg, bg, att, gate);
    kSoftmax<<<256,           256, 0, stream>>>(att, gate);
    kPool   <<<dim3(8, 32),  1024, 0, stream>>>(x, att, pooled);
    kOutInit<<<96,            256, 0, stream>>>(bo, out);
    kGemm   <<<dim3(24, 48),  256, 0, stream>>>(pooled, Wo, out);
}

// Round 6
// 366.984 us; speedup vs baseline: 1.4127x; 1.4127x over previous
//
#include <hip/hip_runtime.h>

// B=32, S=2048, F=768, H=8  — all fp32
// ws layout (floats): att/w [524288] | gate [524288] | pooled [196608] | partial [6291456]

// 512 threads = 8 waves per block; each wave computes 2 rows x 16 logits.
__global__ __launch_bounds__(512) void kLogits(const float* __restrict__ x,
    const float* __restrict__ Wa, const float* __restrict__ ba,
    const float* __restrict__ Wg, const float* __restrict__ bg,
    float* __restrict__ att, float* __restrict__ gate)
{
    __shared__ float Wl[16 * 768];   // rows 0..7 = W_att, 8..15 = W_gate
    int t = threadIdx.x;
    for (int i = t; i < 12288; i += 512)
        Wl[i] = (i < 6144) ? Wa[i] : Wg[i - 6144];
    __syncthreads();

    int wid = t >> 6, lane = t & 63;
    long row0 = (long)blockIdx.x * 16 + wid * 2;   // each wave: 2 rows

    float4 xv[2][3];
    #pragma unroll
    for (int r = 0; r < 2; r++) {
        const float4* xp = reinterpret_cast<const float4*>(x + (row0 + r) * 768 + lane * 4);
        #pragma unroll
        for (int k = 0; k < 3; k++) xv[r][k] = xp[k * 64];
    }

    float acc[32];   // acc[h*2 + r]
    #pragma unroll
    for (int i = 0; i < 32; i++) acc[i] = 0.f;

    #pragma unroll
    for (int h = 0; h < 16; h++) {
        const float4* wp = reinterpret_cast<const float4*>(&Wl[h * 768 + lane * 4]);
        #pragma unroll
        for (int k = 0; k < 3; k++) {
            float4 wv = wp[k * 64];
            #pragma unroll
            for (int r = 0; r < 2; r++) {
                acc[h * 2 + r] += wv.x * xv[r][k].x;
                acc[h * 2 + r] += wv.y * xv[r][k].y;
                acc[h * 2 + r] += wv.z * xv[r][k].z;
                acc[h * 2 + r] += wv.w * xv[r][k].w;
            }
        }
    }

    // reduce-scatter: lane L (and L^32) ends holding full sum of acc[bitrev5(L&31)]
#define RSTEP(STEP, HALF) { \
    int bit = (lane >> STEP) & 1; \
    _Pragma("unroll") \
    for (int i = 0; i < HALF; i++) { \
        float send = bit ? acc[i] : acc[i + HALF]; \
        float recv = __shfl_xor(send, 1 << STEP, 64); \
        acc[i] = (bit ? acc[i + HALF] : acc[i]) + recv; \
    } }
    RSTEP(0, 16) RSTEP(1, 8) RSTEP(2, 4) RSTEP(3, 2) RSTEP(4, 1)
#undef RSTEP
    acc[0] += __shfl_xor(acc[0], 32, 64);

    if (lane < 32) {
        int idx = ((lane & 1) << 4) | (((lane >> 1) & 1) << 3) | (((lane >> 2) & 1) << 2)
                | (((lane >> 3) & 1) << 1) | ((lane >> 4) & 1);
        int h = idx >> 1, r = idx & 1;
        long row = row0 + r;
        int b = (int)(row >> 11);
        int s = (int)(row & 2047);
        if (h < 8) {
            att[((b << 3) + h) * 2048 + s] = acc[0] + ba[h];
        } else {
            float g = acc[0] + bg[h - 8];
            gate[((b << 3) + h - 8) * 2048 + s] = 1.f / (1.f + __expf(-g));
        }
    }
}

// block per (b,h): softmax over S, fold in sigmoid(gate), write w in place of att
__global__ __launch_bounds__(256) void kSoftmax(float* __restrict__ att,
                                                const float* __restrict__ gate)
{
    int bh = blockIdx.x;
    int t = threadIdx.x;
    long base = (long)bh * 2048;

    float v[8];
    #pragma unroll
    for (int i = 0; i < 8; i++) v[i] = att[base + t + (i << 8)];

    float m = v[0];
    #pragma unroll
    for (int i = 1; i < 8; i++) m = fmaxf(m, v[i]);
    #pragma unroll
    for (int off = 1; off < 64; off <<= 1) m = fmaxf(m, __shfl_xor(m, off, 64));

    __shared__ float sm[4], ssum[4];
    int wid = t >> 6, lane = t & 63;
    if (lane == 0) sm[wid] = m;
    __syncthreads();
    float M = fmaxf(fmaxf(sm[0], sm[1]), fmaxf(sm[2], sm[3]));

    float e[8]; float s = 0.f;
    #pragma unroll
    for (int i = 0; i < 8; i++) { e[i] = __expf(v[i] - M); s += e[i]; }
    #pragma unroll
    for (int off = 1; off < 64; off <<= 1) s += __shfl_xor(s, off, 64);
    if (lane == 0) ssum[wid] = s;
    __syncthreads();
    float inv = 1.f / (ssum[0] + ssum[1] + ssum[2] + ssum[3]);

    #pragma unroll
    for (int i = 0; i < 8; i++) {
        long idx = base + t + (i << 8);
        att[idx] = e[i] * inv * gate[idx];
    }
}

// grid (3 fc, 8 sc, 32 b), 256 threads. Each sub-wave s-group (sg) owns 64 s.
// ATOMIC=0: write partial[b][sc*4+sg][h][f] (no atomics). ATOMIC=1: atomicAdd pooled.
template<int ATOMIC>
__global__ __launch_bounds__(256) void kPool(const float* __restrict__ x,
                                             const float* __restrict__ w,
                                             float* __restrict__ outp)
{
    int fc = blockIdx.x, sc = blockIdx.y, b = blockIdx.z;
    int t = threadIdx.x;
    int sg = t >> 6, lane = t & 63;
    int s0 = sc << 8;

    __shared__ float wl[2048];           // transposed: wl[ss*8 + h]
    for (int i = t; i < 2048; i += 256)
        wl[i] = w[((long)((b << 3) + (i & 7)) << 11) + s0 + (i >> 3)];
    __syncthreads();

    float4 acc[8];
    #pragma unroll
    for (int h = 0; h < 8; h++) acc[h] = make_float4(0.f, 0.f, 0.f, 0.f);

    const float4* xb = reinterpret_cast<const float4*>(
        x + ((long)(b << 11) + s0 + (sg << 6)) * 768 + (fc << 8) + (lane << 2));
    const float4* wrow = reinterpret_cast<const float4*>(wl + (sg << 6) * 8);

    #pragma unroll 4
    for (int i = 0; i < 64; i++) {
        float4 xv = xb[i * 192];                  // row stride 768 floats
        float4 w0 = wrow[i * 2], w1 = wrow[i * 2 + 1];   // broadcast, conflict-free
        acc[0].x += w0.x * xv.x; acc[0].y += w0.x * xv.y; acc[0].z += w0.x * xv.z; acc[0].w += w0.x * xv.w;
        acc[1].x += w0.y * xv.x; acc[1].y += w0.y * xv.y; acc[1].z += w0.y * xv.z; acc[1].w += w0.y * xv.w;
        acc[2].x += w0.z * xv.x; acc[2].y += w0.z * xv.y; acc[2].z += w0.z * xv.z; acc[2].w += w0.z * xv.w;
        acc[3].x += w0.w * xv.x; acc[3].y += w0.w * xv.y; acc[3].z += w0.w * xv.z; acc[3].w += w0.w * xv.w;
        acc[4].x += w1.x * xv.x; acc[4].y += w1.x * xv.y; acc[4].z += w1.x * xv.z; acc[4].w += w1.x * xv.w;
        acc[5].x += w1.y * xv.x; acc[5].y += w1.y * xv.y; acc[5].z += w1.y * xv.z; acc[5].w += w1.y * xv.w;
        acc[6].x += w1.z * xv.x; acc[6].y += w1.z * xv.y; acc[6].z += w1.z * xv.z; acc[6].w += w1.z * xv.w;
        acc[7].x += w1.w * xv.x; acc[7].y += w1.w * xv.y; acc[7].z += w1.w * xv.z; acc[7].w += w1.w * xv.w;
    }

    if (ATOMIC) {
        int fbase = (fc << 8) + (lane << 2);
        #pragma unroll
        for (int h = 0; h < 8; h++) {
            atomicAdd(&outp[b * 6144 + (fbase + 0) * 8 + h], acc[h].x);
            atomicAdd(&outp[b * 6144 + (fbase + 1) * 8 + h], acc[h].y);
            atomicAdd(&outp[b * 6144 + (fbase + 2) * 8 + h], acc[h].z);
            atomicAdd(&outp[b * 6144 + (fbase + 3) * 8 + h], acc[h].w);
        }
    } else {
        int slice = (sc << 2) + sg;
        float4* pp = reinterpret_cast<float4*>(
            outp + (long)(((b << 5) + slice) * 8) * 768 + (fc << 8) + (lane << 2));
        #pragma unroll
        for (int h = 0; h < 8; h++) pp[h * 192] = acc[h];
    }
}

// grid (3 fc, 4 hq, 32 b), 256 threads: pooled[b, f*8 + hq*2 .. +1] = sum of 32 slices
__global__ __launch_bounds__(256) void kPoolReduce(const float* __restrict__ partial,
                                                   float* __restrict__ pooled)
{
    int f  = blockIdx.x * 256 + threadIdx.x;   // 0..767
    int hq = blockIdx.y;                       // 0..3
    int b  = blockIdx.z;                       // 0..31
    float s0 = 0.f, s1 = 0.f;
    const float* p = partial + ((long)(b << 5) * 8 + (hq << 1)) * 768 + f;
    #pragma unroll 4
    for (int sl = 0; sl < 32; sl++) {
        s0 += p[0];
        s1 += p[768];
        p += 8 * 768;
    }
    float2* o = reinterpret_cast<float2*>(pooled + b * 6144 + (f << 3) + (hq << 1));
    *o = make_float2(s0, s1);
}

__global__ __launch_bounds__(256) void kOutInit(const float* __restrict__ bo,
                                                float* __restrict__ out)
{
    int idx = blockIdx.x * 256 + threadIdx.x;   // 24576 total
    out[idx] = bo[idx % 768];
}

// out[b,fo] += sum_k pooled[b,k]*Wout[fo,k]; block = (k-chunk 256, fo-chunk 16)
__global__ __launch_bounds__(256) void kGemm(const float* __restrict__ pooled,
                                             const float* __restrict__ Wout,
                                             float* __restrict__ out)
{
    int kg = blockIdx.x, fg = blockIdx.y;
    int k0 = kg << 8, fo0 = fg << 4;
    __shared__ float pl[32 * 258];
    __shared__ float wl[16 * 258];
    int t = threadIdx.x;
    #pragma unroll 4
    for (int i = 0; i < 32; i++) pl[i * 258 + t] = pooled[i * 6144 + k0 + t];
    #pragma unroll 4
    for (int j = 0; j < 16; j++) wl[j * 258 + t] = Wout[(fo0 + j) * 6144 + k0 + t];
    __syncthreads();

    int b = t & 31, fq = t >> 5;
    const float2* pp = reinterpret_cast<const float2*>(pl + b * 258);
    const float2* u  = reinterpret_cast<const float2*>(wl + fq * 258);
    const float2* vv = reinterpret_cast<const float2*>(wl + (fq + 8) * 258);
    float a0 = 0.f, a1 = 0.f;
    #pragma unroll 8
    for (int kk = 0; kk < 128; kk++) {
        float2 p = pp[kk], w0 = u[kk], w1 = vv[kk];
        a0 += p.x * w0.x + p.y * w0.y;
        a1 += p.x * w1.x + p.y * w1.y;
    }
    atomicAdd(&out[b * 768 + fo0 + fq], a0);
    atomicAdd(&out[b * 768 + fo0 + 8 + fq], a1);
}

extern "C" void kernel_launch(void* const* d_in, const int* in_sizes, int n_in,
                              void* d_out, int out_size, void* d_ws, size_t ws_size,
                              hipStream_t stream)
{
    const float* x  = (const float*)d_in[0];
    const float* Wa = (const float*)d_in[1];
    const float* ba = (const float*)d_in[2];
    const float* Wg = (const float*)d_in[3];
    const float* bg = (const float*)d_in[4];
    const float* Wo = (const float*)d_in[5];
    const float* bo = (const float*)d_in[6];
    float* out = (float*)d_out;

    float* att     = (float*)d_ws;             // 524288 floats (becomes w in place)
    float* gate    = att + 524288;             // 524288 floats
    float* pooled  = gate + 524288;            // 196608 floats
    float* partial = pooled + 196608;          // 6291456 floats

    const size_t need = (size_t)(524288 * 2 + 196608 + 6291456) * sizeof(float);
    bool use_partial = ws_size >= need;

    kLogits <<<4096, 512, 0, stream>>>(x, Wa, ba, Wg, bg, att, gate);
    kSoftmax<<<256,  256, 0, stream>>>(att, gate);

    if (use_partial) {
        kPool<0>   <<<dim3(3, 8, 32), 256, 0, stream>>>(x, att, partial);
        kPoolReduce<<<dim3(3, 4, 32), 256, 0, stream>>>(partial, pooled);
    } else {
        hipMemsetAsync(pooled, 0, 196608 * sizeof(float), stream);
        kPool<1>   <<<dim3(3, 8, 32), 256, 0, stream>>>(x, att, pooled);
    }

    kOutInit<<<96,           256, 0, stream>>>(bo, out);
    kGemm   <<<dim3(24, 48), 256, 0, stream>>>(pooled, Wo, out);
}